// Round 6
// baseline (2775.499 us; speedup 1.0000x reference)
//
#include <hip/hip_runtime.h>
#include <cmath>

// ---------------- bf16 helpers ----------------
__device__ __forceinline__ float bflo(unsigned int u) {
  union { unsigned int i; float f; } v; v.i = u << 16; return v.f;
}
__device__ __forceinline__ float bfhi(unsigned int u) {
  union { unsigned int i; float f; } v; v.i = u & 0xffff0000u; return v.f;
}
__device__ __forceinline__ float bf2f(unsigned short u) {
  union { unsigned int i; float f; } v; v.i = ((unsigned int)u) << 16; return v.f;
}
__device__ __forceinline__ unsigned short f2bf(float f) {
  union { float f; unsigned int i; } v; v.f = f;
  unsigned int i = v.i;
  return (unsigned short)((i + 0x7fffu + ((i >> 16) & 1u)) >> 16);  // RNE
}
__device__ __forceinline__ unsigned int pk2bf(float a, float b) {
  return (unsigned int)f2bf(a) | ((unsigned int)f2bf(b) << 16);
}

typedef __attribute__((ext_vector_type(8))) short short8;
typedef __attribute__((ext_vector_type(4))) float floatx4;

// ======== MFMA GEMM v2: C[M,N] = act(A_bf16[M,K] @ W_f32[N,K]^T + bias) ========
// - W converted fp32->bf16 at stage time (no separate conv kernels / buffers)
// - double-buffered LDS, ONE barrier per K-iter (drain covers loads issued a
//   full compute-phase earlier)
// - 1-D grid with XCD-colocating swizzle: supergroups of 8 m-tiles x Nt
//   n-tiles, m fastest mod 8 -> blocks sharing an A-tile share blockIdx%8
//   (round-robin XCD) -> A-tile lives in ONE XCD's L2.
__global__ __launch_bounds__(256) void gemm_mfma(
    const unsigned short* __restrict__ A, int lda,
    const float* __restrict__ W, int ldw,
    const float* __restrict__ bias,
    void* __restrict__ Cv, int ldc,
    int K, int act, int cbf16, int Mt, int Nt)
{
  __shared__ __align__(16) unsigned short As[2][128 * 32];
  __shared__ __align__(16) unsigned short Ws[2][128 * 32];
  const int tid = threadIdx.x;
  const int wave = tid >> 6, lane = tid & 63;

  // ---- block swizzle ----
  int m_t, n_t;
  {
    int b = blockIdx.x;
    int gsz = Nt << 3;               // blocks per full supergroup
    int fullG = Mt >> 3;
    int fullB = fullG * gsz;
    if (b < fullB) {
      int g = b / gsz, rem = b % gsz;
      m_t = (g << 3) + (rem & 7);
      n_t = rem >> 3;
    } else {
      int rem = b - fullB;
      int mbase = fullG << 3;
      int msize = Mt - mbase;        // 1..7
      m_t = mbase + rem % msize;
      n_t = rem / msize;
    }
  }
  const int bm = m_t * 128, bn = n_t * 128;
  const int wm = (wave >> 1) << 6, wn = (wave & 1) << 6;

  floatx4 acc[4][4];
#pragma unroll
  for (int i = 0; i < 4; ++i)
#pragma unroll
    for (int j = 0; j < 4; ++j) acc[i][j] = (floatx4){0.f, 0.f, 0.f, 0.f};

  // A staging: wave stages rows [wave*32, wave*32+32), glds width 16
  const int srow = (wave << 5) + (lane >> 2);
  const int scol = (lane & 3) << 3;
  const unsigned short* Ag  = A + (size_t)(bm + srow) * lda + scol;
  const unsigned short* Ag2 = Ag + (size_t)16 * lda;
  // W staging: thread handles 16 f32 of one row-half
  const int wrow = tid >> 1;
  const int wcol = (tid & 1) << 4;
  const float* Wg = W + (size_t)(bn + wrow) * ldw + wcol;

  // fragment read offsets
  const int a_off = (wm + (lane & 15)) * 32 + ((lane >> 4) << 3);
  const int b_off = (wn + (lane & 15)) * 32 + ((lane >> 4) << 3);

  const int niter = K >> 5;

#define STAGE(itx, sb)                                                               \
  {                                                                                  \
    const int k0 = (itx) << 5;                                                       \
    __builtin_amdgcn_global_load_lds(                                                \
        (const __attribute__((address_space(1))) unsigned int*)(Ag + k0),            \
        (__attribute__((address_space(3))) unsigned int*)(&As[sb][(wave << 5) * 32]),\
        16, 0, 0);                                                                   \
    __builtin_amdgcn_global_load_lds(                                                \
        (const __attribute__((address_space(1))) unsigned int*)(Ag2 + k0),           \
        (__attribute__((address_space(3))) unsigned int*)(&As[sb][((wave << 5) + 16) * 32]),\
        16, 0, 0);                                                                   \
    const float* wp = Wg + k0;                                                       \
    float4 w0 = *(const float4*)(wp);                                                \
    float4 w1 = *(const float4*)(wp + 4);                                            \
    float4 w2 = *(const float4*)(wp + 8);                                            \
    float4 w3 = *(const float4*)(wp + 12);                                           \
    uint4 o0, o1;                                                                    \
    o0.x = pk2bf(w0.x, w0.y); o0.y = pk2bf(w0.z, w0.w);                              \
    o0.z = pk2bf(w1.x, w1.y); o0.w = pk2bf(w1.z, w1.w);                              \
    o1.x = pk2bf(w2.x, w2.y); o1.y = pk2bf(w2.z, w2.w);                              \
    o1.z = pk2bf(w3.x, w3.y); o1.w = pk2bf(w3.z, w3.w);                              \
    *(uint4*)&Ws[sb][wrow * 32 + wcol] = o0;                                         \
    *(uint4*)&Ws[sb][wrow * 32 + wcol + 8] = o1;                                     \
  }

  STAGE(0, 0);

  for (int it = 0; it < niter; ++it) {
    const int buf = it & 1;
    __syncthreads();   // drains prev stage loads + all reads of buf done
    // fragment reads FIRST (so MFMA's lgkm wait doesn't cover staging writes)
    short8 af[4], bf[4];
#pragma unroll
    for (int i = 0; i < 4; ++i) {
      af[i] = *reinterpret_cast<const short8*>(&As[buf][a_off + (i << 4) * 32]);
      bf[i] = *reinterpret_cast<const short8*>(&Ws[buf][b_off + (i << 4) * 32]);
    }
    if (it + 1 < niter) STAGE(it + 1, buf ^ 1);
#pragma unroll
    for (int i = 0; i < 4; ++i)
#pragma unroll
      for (int j = 0; j < 4; ++j)
        acc[i][j] = __builtin_amdgcn_mfma_f32_16x16x32_bf16(af[i], bf[j], acc[i][j], 0, 0, 0);
  }
#undef STAGE

  const int col0 = lane & 15;
  const int row0 = (lane >> 4) << 2;
#pragma unroll
  for (int i = 0; i < 4; ++i) {
#pragma unroll
    for (int j = 0; j < 4; ++j) {
      int col = bn + wn + (j << 4) + col0;
      float bv = bias ? bias[col] : 0.f;
#pragma unroll
      for (int r = 0; r < 4; ++r) {
        int row = bm + wm + (i << 4) + row0 + r;
        float v = acc[i][j][r] + bv;
        if (act) v = 0.5f * v * (1.f + erff(v * 0.70710678f));  // exact GELU
        if (cbf16) ((unsigned short*)Cv)[(size_t)row * ldc + col] = f2bf(v);
        else       ((float*)Cv)[(size_t)row * ldc + col] = v;
      }
    }
  }
}

// ---------------- wave reductions ----------------
__device__ __forceinline__ float wred_max(float v) {
#pragma unroll
  for (int off = 32; off > 0; off >>= 1) v = fmaxf(v, __shfl_xor(v, off, 64));
  return v;
}
__device__ __forceinline__ float wred_sum(float v) {
#pragma unroll
  for (int off = 32; off > 0; off >>= 1) v += __shfl_xor(v, off, 64);
  return v;
}

// ============ MFMA cross-attention (flash, 2 k-groups, in-block merge) ============
#define LDK 72
__global__ __launch_bounds__(512) void attn_mfma_kernel(
    const unsigned short* __restrict__ Qp,   // [bg*60][512] bf16
    const unsigned short* __restrict__ KVb,  // [bg*1800][1024] bf16: K|V
    unsigned short* __restrict__ O,          // [bg*60][512] bf16
    const int* __restrict__ tt, const int* __restrict__ ut,
    const unsigned char* __restrict__ km,
    const float* __restrict__ rel)           // rpe[l]: [32][8]
{
  const int bg = blockIdx.x >> 3, h = blockIdx.x & 7;
  const int tid = threadIdx.x;
  const int grp = tid >> 8;
  const int wave = (tid >> 6) & 3;
  const int lane = tid & 63;
  const int quad = lane >> 4, mrow = lane & 15;

  __shared__ __align__(16) unsigned short SMEM[6 * 64 * LDK];
  unsigned short* Ks = SMEM + grp * (3 * 64 * LDK);
  unsigned short* Vt = Ks + 64 * LDK;
  unsigned short* Ps = Vt + 64 * LDK;

  const int qa = wave * 16 + mrow;
  const int qc = qa < 60 ? qa : 59;
  const unsigned short* qptr = Qp + (size_t)(bg * 60 + qc) * 512 + h * 64 + quad * 8;
  const short8 af0 = *reinterpret_cast<const short8*>(qptr);
  const short8 af1 = *reinterpret_cast<const short8*>(qptr + 32);

  const float relreg = rel[(lane & 31) * 8 + h];

  int tq[4];
  float m[4], l[4];
  floatx4 acc[4];
#pragma unroll
  for (int r = 0; r < 4; ++r) {
    int qo = wave * 16 + quad * 4 + r;
    tq[r] = ut[bg * 60 + (qo < 60 ? qo : 59)];
    m[r] = grp ? -1e30f : 0.f;
    l[r] = grp ? 0.f : 1.f;
  }
#pragma unroll
  for (int nt = 0; nt < 4; ++nt) acc[nt] = (floatx4){0.f, 0.f, 0.f, 0.f};

  const int sk = tid & 255;
  const int stok = sk >> 2, schk = sk & 3;

  for (int it = 0; it < 15; ++it) {
    const int k0 = (grp + 2 * it) << 6;
    __syncthreads();
    {
      const int key = k0 + stok;
      uint4 kr0 = {0,0,0,0}, kr1 = {0,0,0,0}, vr0 = {0,0,0,0}, vr1 = {0,0,0,0};
      if (key < 1800) {
        const unsigned short* kb = KVb + ((size_t)bg * 1800 + key) * 1024 + h * 64 + schk * 16;
        kr0 = *reinterpret_cast<const uint4*>(kb);
        kr1 = *reinterpret_cast<const uint4*>(kb + 8);
        vr0 = *reinterpret_cast<const uint4*>(kb + 512);
        vr1 = *reinterpret_cast<const uint4*>(kb + 520);
      }
      *reinterpret_cast<uint4*>(&Ks[stok * LDK + schk * 16]) = kr0;
      *reinterpret_cast<uint4*>(&Ks[stok * LDK + schk * 16 + 8]) = kr1;
      unsigned int wv[8] = {vr0.x, vr0.y, vr0.z, vr0.w, vr1.x, vr1.y, vr1.z, vr1.w};
#pragma unroll
      for (int e = 0; e < 16; ++e)
        Vt[(schk * 16 + e) * LDK + stok] = (unsigned short)(wv[e >> 1] >> ((e & 1) * 16));
    }
    int meta = 0x10000;
    {
      int kk = k0 + lane;
      if (kk < 1800) {
        int base = bg * 1800 + kk;
        meta = tt[base] | (km[base] ? 0x10000 : 0);
      }
    }
    __syncthreads();

    floatx4 S[4];
#pragma unroll
    for (int nt = 0; nt < 4; ++nt) {
      const unsigned short* kb = Ks + (nt * 16 + mrow) * LDK + quad * 8;
      short8 b0 = *reinterpret_cast<const short8*>(kb);
      short8 b1 = *reinterpret_cast<const short8*>(kb + 32);
      floatx4 s = (floatx4){0.f, 0.f, 0.f, 0.f};
      s = __builtin_amdgcn_mfma_f32_16x16x32_bf16(af0, b0, s, 0, 0, 0);
      s = __builtin_amdgcn_mfma_f32_16x16x32_bf16(af1, b1, s, 0, 0, 0);
      S[nt] = s;
    }
    int mcol[4];
#pragma unroll
    for (int nt = 0; nt < 4; ++nt)
      mcol[nt] = __builtin_amdgcn_ds_bpermute((nt * 16 + mrow) << 2, meta);
    float sv[4][4];
#pragma unroll
    for (int nt = 0; nt < 4; ++nt) {
      int tk = mcol[nt] & 0xffff;
      int bad0 = mcol[nt] >> 16;
#pragma unroll
      for (int r = 0; r < 4; ++r) {
        float v = S[nt][r] * 0.125f;
        int ridx = (tq[r] - tk) & 31;
        v += __int_as_float(__builtin_amdgcn_ds_bpermute(ridx << 2, __float_as_int(relreg)));
        sv[nt][r] = (bad0 | (tk >= tq[r])) ? -1e30f : v;
      }
    }
#pragma unroll
    for (int r = 0; r < 4; ++r) {
      float rm = fmaxf(fmaxf(sv[0][r], sv[1][r]), fmaxf(sv[2][r], sv[3][r]));
#pragma unroll
      for (int d = 1; d < 16; d <<= 1) rm = fmaxf(rm, __shfl_xor(rm, d, 64));
      float nm = fmaxf(m[r], rm);
      float corr = __expf(m[r] - nm);
      float ps = 0.f;
      const int prow = (wave * 16 + quad * 4 + r) * LDK + mrow;
#pragma unroll
      for (int nt = 0; nt < 4; ++nt) {
        float p = __expf(sv[nt][r] - nm);
        ps += p;
        Ps[prow + nt * 16] = f2bf(p);
      }
#pragma unroll
      for (int d = 1; d < 16; d <<= 1) ps += __shfl_xor(ps, d, 64);
      l[r] = l[r] * corr + ps;
      m[r] = nm;
#pragma unroll
      for (int nt = 0; nt < 4; ++nt) acc[nt][r] *= corr;
    }
    const unsigned short* pp = Ps + (wave * 16 + mrow) * LDK + quad * 8;
    short8 a0 = *reinterpret_cast<const short8*>(pp);
    short8 a1 = *reinterpret_cast<const short8*>(pp + 32);
#pragma unroll
    for (int nt = 0; nt < 4; ++nt) {
      const unsigned short* vb = Vt + (nt * 16 + mrow) * LDK + quad * 8;
      short8 b0 = *reinterpret_cast<const short8*>(vb);
      short8 b1 = *reinterpret_cast<const short8*>(vb + 32);
      acc[nt] = __builtin_amdgcn_mfma_f32_16x16x32_bf16(a0, b0, acc[nt], 0, 0, 0);
      acc[nt] = __builtin_amdgcn_mfma_f32_16x16x32_bf16(a1, b1, acc[nt], 0, 0, 0);
    }
  }

  __syncthreads();
  float* MA = (float*)SMEM;
  float* Ml = (float*)(SMEM + 64 * 68 * 2);
  float* Ll = Ml + 64;
  if (grp == 1) {
#pragma unroll
    for (int r = 0; r < 4; ++r) {
      int row = wave * 16 + quad * 4 + r;
#pragma unroll
      for (int nt = 0; nt < 4; ++nt)
        MA[row * 68 + nt * 16 + mrow] = acc[nt][r];
      if (mrow == 0) { Ml[row] = m[r]; Ll[row] = l[r]; }
    }
  }
  __syncthreads();
  if (grp == 0) {
#pragma unroll
    for (int r = 0; r < 4; ++r) {
      int row = wave * 16 + quad * 4 + r;
      float m1 = Ml[row], l1 = Ll[row];
      float M = fmaxf(m[r], m1);
      float c0 = __expf(m[r] - M), c1 = __expf(m1 - M);
      float invL = 1.f / (l[r] * c0 + l1 * c1);
      if (row < 60) {
        unsigned short* op = O + (size_t)(bg * 60 + row) * 512 + h * 64;
#pragma unroll
        for (int nt = 0; nt < 4; ++nt) {
          float o = (acc[nt][r] * c0 + MA[row * 68 + nt * 16 + mrow] * c1) * invL;
          op[nt * 16 + mrow] = f2bf(o);
        }
      }
    }
  }
}

// ---------------- VALU flash attention (self-attn, kLen=60) ----------------
#define QPB 32
#define QPW 8
__global__ __launch_bounds__(256) void attn2_kernel(
    const unsigned short* __restrict__ Qp, int qs,
    const unsigned short* __restrict__ Kp, int ks,
    const unsigned short* __restrict__ Vp, int vs,
    unsigned short* __restrict__ O, int os, int kLen,
    const unsigned char* __restrict__ kmask)
{
  const int bg = blockIdx.x >> 3;
  const int h  = blockIdx.x & 7;
  const int q0 = blockIdx.y * QPB;
  const int tid = threadIdx.x;
  const int wave = tid >> 6, lane = tid & 63;

  __shared__ float Qs[QPB][68];
  __shared__ float Ks[64][68];
  __shared__ float Vs[64][68];
  __shared__ float Ps[QPB][68];

  {
    int qr = tid >> 3, j = tid & 7;
    int q = q0 + qr;
    float f[8] = {0, 0, 0, 0, 0, 0, 0, 0};
    if (q < 60) {
      uint4 v = *reinterpret_cast<const uint4*>(Qp + (size_t)(bg * 60 + q) * qs + h * 64 + j * 8);
      f[0] = bflo(v.x); f[1] = bfhi(v.x); f[2] = bflo(v.y); f[3] = bfhi(v.y);
      f[4] = bflo(v.z); f[5] = bfhi(v.z); f[6] = bflo(v.w); f[7] = bfhi(v.w);
    }
#pragma unroll
    for (int e = 0; e < 8; ++e) Qs[qr][j * 8 + e] = f[e];
  }

  float m[QPW], l[QPW], acc[QPW];
#pragma unroll
  for (int i = 0; i < QPW; ++i) { m[i] = 0.f; l[i] = 1.f; acc[i] = 0.f; }

  const int std = tid >> 2;
  const int stj = tid & 3;

  for (int k0 = 0; k0 < kLen; k0 += 64) {
    __syncthreads();
    const bool sok = (k0 + std) < kLen;
    {
      const unsigned short* kb = Kp + ((size_t)bg * kLen + k0 + std) * ks + h * 64 + stj * 16;
      float f[16];
#pragma unroll
      for (int e = 0; e < 16; ++e) f[e] = 0.f;
      if (sok) {
        uint4 v0 = *reinterpret_cast<const uint4*>(kb);
        uint4 v1 = *reinterpret_cast<const uint4*>(kb + 8);
        f[0] = bflo(v0.x); f[1] = bfhi(v0.x); f[2]  = bflo(v0.y); f[3]  = bfhi(v0.y);
        f[4] = bflo(v0.z); f[5] = bfhi(v0.z); f[6]  = bflo(v0.w); f[7]  = bfhi(v0.w);
        f[8] = bflo(v1.x); f[9] = bfhi(v1.x); f[10] = bflo(v1.y); f[11] = bfhi(v1.y);
        f[12] = bflo(v1.z); f[13] = bfhi(v1.z); f[14] = bflo(v1.w); f[15] = bfhi(v1.w);
      }
#pragma unroll
      for (int e = 0; e < 16; ++e) Ks[stj * 16 + e][std] = f[e];
    }
    {
      const unsigned short* vb = Vp + ((size_t)bg * kLen + k0 + std) * vs + h * 64;
#pragma unroll
      for (int c = 0; c < 2; ++c) {
        int off = c * 32 + stj * 8;
        float f[8] = {0, 0, 0, 0, 0, 0, 0, 0};
        if (sok) {
          uint4 v = *reinterpret_cast<const uint4*>(vb + off);
          f[0] = bflo(v.x); f[1] = bfhi(v.x); f[2] = bflo(v.y); f[3] = bfhi(v.y);
          f[4] = bflo(v.z); f[5] = bfhi(v.z); f[6] = bflo(v.w); f[7] = bfhi(v.w);
        }
#pragma unroll
        for (int e = 0; e < 8; ++e) Vs[std][off + e] = f[e];
      }
    }
    const int kk = k0 + lane;
    const bool kok = kk < kLen;
    unsigned char kmv = 0;
    if (kok && kmask) kmv = kmask[(size_t)bg * kLen + kk];
    __syncthreads();

    float s[QPW];
#pragma unroll
    for (int i = 0; i < QPW; ++i) s[i] = 0.f;
    for (int d = 0; d < 64; ++d) {
      float kv = Ks[d][lane];
#pragma unroll
      for (int i = 0; i < QPW; ++i)
        s[i] = fmaf(Qs[wave * QPW + i][d], kv, s[i]);
    }

    const int kmax = min(64, kLen - k0);
#pragma unroll
    for (int i = 0; i < QPW; ++i) {
      float svv = s[i] * 0.125f;
      if (kmv || !kok) svv = -1e30f;
      float nm = fmaxf(m[i], wred_max(svv));
      float p = __expf(svv - nm);
      float ts = wred_sum(p);
      float corr = __expf(m[i] - nm);
      l[i] = l[i] * corr + ts;
      acc[i] *= corr;
      m[i] = nm;
      Ps[wave * QPW + i][lane] = p;
    }
    for (int k = 0; k < kmax; ++k) {
      float v = Vs[k][lane];
#pragma unroll
      for (int i = 0; i < QPW; ++i)
        acc[i] = fmaf(Ps[wave * QPW + i][k], v, acc[i]);
    }
  }

#pragma unroll
  for (int i = 0; i < QPW; ++i) {
    int q = q0 + wave * QPW + i;
    if (q < 60)
      O[(size_t)(bg * 60 + q) * os + h * 64 + lane] = f2bf(acc[i] / l[i]);
  }
}

// ---------------- residual add + LayerNorm (E=512), dual fp32+bf16 out ----------------
__global__ __launch_bounds__(256) void add_ln_kernel(
    const float* __restrict__ a, const float* __restrict__ b,
    const float* __restrict__ g, const float* __restrict__ be,
    float* __restrict__ o, unsigned short* __restrict__ ob)
{
  const int t = blockIdx.x;
  const int tid = threadIdx.x;
  const int wave = tid >> 6, lane = tid & 63;
  const size_t base = (size_t)t * 512;
  float v0 = a[base + tid] + b[base + tid];
  float v1 = a[base + 256 + tid] + b[base + 256 + tid];
  __shared__ float red[4];
  float s = wred_sum(v0 + v1);
  if (lane == 0) red[wave] = s;
  __syncthreads();
  float mean = (red[0] + red[1] + red[2] + red[3]) * (1.0f / 512.0f);
  float d0 = v0 - mean, d1 = v1 - mean;
  float vs = wred_sum(d0 * d0 + d1 * d1);
  __syncthreads();
  if (lane == 0) red[wave] = vs;
  __syncthreads();
  float var = (red[0] + red[1] + red[2] + red[3]) * (1.0f / 512.0f);
  float rstd = rsqrtf(var + 1e-5f);
  float r0 = d0 * rstd * g[tid] + be[tid];
  float r1 = d1 * rstd * g[256 + tid] + be[256 + tid];
  o[base + tid] = r0;
  o[base + 256 + tid] = r1;
  ob[base + tid] = f2bf(r0);
  ob[base + 256 + tid] = f2bf(r1);
}

// ---------------- embedding builders ----------------
__global__ __launch_bounds__(256) void build_traj_kernel(
    const float* __restrict__ tf, const int* __restrict__ ids,
    const float* __restrict__ Ww, unsigned short* __restrict__ traj)
{
  int idx = blockIdx.x * 256 + threadIdx.x;
  int tok = idx >> 9;
  int j = idx & 511;
  float v = (j < 256) ? tf[((size_t)tok << 8) + j] : Ww[(j - 256) * 51 + ids[tok]];
  traj[idx] = f2bf(v);
}

__global__ __launch_bounds__(256) void build_unk_kernel(
    const float* __restrict__ uf, const float* __restrict__ Ww,
    float* __restrict__ x, unsigned short* __restrict__ xb)
{
  int idx = blockIdx.x * 256 + threadIdx.x;
  int tok = idx >> 9;
  int j = idx & 511;
  float v = (j < 256) ? uf[((size_t)tok << 8) + j] : Ww[(j - 256) * 51 + 50];
  x[idx] = v;
  xb[idx] = f2bf(v);
}

// ---------------- final head ----------------
__global__ __launch_bounds__(64) void head_kernel(
    const float* __restrict__ x, const float* __restrict__ Wout, float* __restrict__ out)
{
  const int t = blockIdx.x;
  const int tid = threadIdx.x;
  __shared__ float xs[256];
  for (int i = tid; i < 256; i += 64) xs[i] = x[(size_t)t * 512 + 256 + i];
  __syncthreads();
  if (tid < 51) {
    const float* w = Wout + tid * 256;
    float s = 0.f;
    for (int k = 0; k < 256; ++k) s = fmaf(xs[k], w[k], s);
    out[t * 51 + tid] = s;
  }
}

// ---------------- orchestration ----------------
extern "C" void kernel_launch(void* const* d_in, const int* in_sizes, int n_in,
                              void* d_out, int out_size, void* d_ws, size_t ws_size,
                              hipStream_t stream) {
  const float* tf  = (const float*)d_in[0];
  const float* uf  = (const float*)d_in[1];
  const int*   ids = (const int*)d_in[2];
  const int*   tt  = (const int*)d_in[3];
  const int*   ut  = (const int*)d_in[4];
  const unsigned char* tm = (const unsigned char*)d_in[5];
  const unsigned char* um = (const unsigned char*)d_in[6];
  const float* Ww   = (const float*)d_in[8];
  const float* Wout = (const float*)d_in[9];
  const float* rpe  = (const float*)d_in[10];
  const float* saW  = (const float*)d_in[11];
  const float* sab  = (const float*)d_in[12];
  const float* saO  = (const float*)d_in[13];
  const float* saob = (const float*)d_in[14];
  const float* sag  = (const float*)d_in[15];
  const float* sabn = (const float*)d_in[16];
  const float* caW  = (const float*)d_in[17];
  const float* cab  = (const float*)d_in[18];
  const float* caO  = (const float*)d_in[19];
  const float* caob = (const float*)d_in[20];
  const float* cag  = (const float*)d_in[21];
  const float* cabn = (const float*)d_in[22];
  const float* f1   = (const float*)d_in[23];
  const float* fb1  = (const float*)d_in[24];
  const float* f2   = (const float*)d_in[25];
  const float* fb2  = (const float*)d_in[26];
  const float* fg   = (const float*)d_in[27];
  const float* fbn  = (const float*)d_in[28];

  // ---- workspace layout (~201 MB) ----
  unsigned short* trajb = (unsigned short*)d_ws;         // 57600*512 bf16
  unsigned short* KVb   = trajb + (size_t)29491200;      // 57600*1024 bf16 (K|V token-major)
  unsigned short* qkvb  = KVb   + (size_t)58982400;      // 1920*1536 bf16
  unsigned short* hb    = qkvb  + (size_t)2949120;       // 1920*2048 bf16
  unsigned short* xb    = hb    + (size_t)3932160;       // 1920*512 bf16
  float* x    = (float*)(xb + (size_t)983040);           // 1920*512 fp32
  float* ybuf = x + (size_t)983040;                      // 1920*512 fp32

  build_traj_kernel<<<dim3(115200), dim3(256), 0, stream>>>(tf, ids, Ww, trajb);
  build_unk_kernel<<<dim3(3840), dim3(256), 0, stream>>>(uf, Ww, x, xb);

  for (int l = 0; l < 6; ++l) {
    if (l > 0) {
      int sl = l - 1;
      // self-attn fused QKV: [1920,512] @ [1536,512]^T -> [1920,1536] bf16
      gemm_mfma<<<dim3(180), dim3(256), 0, stream>>>(
          xb, 512, saW + (size_t)sl * 786432, 512, sab + sl * 1536,
          qkvb, 1536, 512, 0, 1, 15, 12);
      attn2_kernel<<<dim3(256, 2), dim3(256), 0, stream>>>(
          qkvb, 1536, qkvb + 512, 1536, qkvb + 1024, 1536, hb, 512, 60, um);
      gemm_mfma<<<dim3(60), dim3(256), 0, stream>>>(
          hb, 512, saO + (size_t)sl * 262144, 512, saob + sl * 512,
          ybuf, 512, 512, 0, 0, 15, 4);
      add_ln_kernel<<<dim3(1920), dim3(256), 0, stream>>>(x, ybuf, sag + sl * 512, sabn + sl * 512, x, xb);
    }
    // cross-attn K|V: [57600,512] @ [1024,512]^T -> [57600,1024] bf16 token-major
    gemm_mfma<<<dim3(3600), dim3(256), 0, stream>>>(
        trajb, 512, caW + (size_t)l * 786432 + 262144, 512, cab + l * 1536 + 512,
        KVb, 1024, 512, 0, 1, 450, 8);
    // cross-attn Q: [1920,512]
    gemm_mfma<<<dim3(60), dim3(256), 0, stream>>>(
        xb, 512, caW + (size_t)l * 786432, 512, cab + l * 1536,
        qkvb, 512, 512, 0, 1, 15, 4);
    attn_mfma_kernel<<<dim3(256), dim3(512), 0, stream>>>(
        qkvb, KVb, hb, tt, ut, tm, rpe + l * 256);
    gemm_mfma<<<dim3(60), dim3(256), 0, stream>>>(
        hb, 512, caO + (size_t)l * 262144, 512, caob + l * 512,
        ybuf, 512, 512, 0, 0, 15, 4);
    add_ln_kernel<<<dim3(1920), dim3(256), 0, stream>>>(x, ybuf, cag + l * 512, cabn + l * 512, x, xb);
    // FFN1 + exact GELU: [1920,512] @ [2048,512]^T -> [1920,2048] bf16
    gemm_mfma<<<dim3(240), dim3(256), 0, stream>>>(
        xb, 512, f1 + (size_t)l * 1048576, 512, fb1 + l * 2048,
        hb, 2048, 512, 1, 1, 15, 16);
    // FFN2: [1920,2048] @ [512,2048]^T -> [1920,512] fp32
    gemm_mfma<<<dim3(60), dim3(256), 0, stream>>>(
        hb, 2048, f2 + (size_t)l * 1048576, 2048, fb2 + l * 512,
        ybuf, 512, 2048, 0, 0, 15, 4);
    add_ln_kernel<<<dim3(1920), dim3(256), 0, stream>>>(x, ybuf, fg + l * 512, fbn + l * 512, x, xb);
  }
  head_kernel<<<dim3(1920), dim3(64), 0, stream>>>(x, Wout, (float*)d_out);
}